// Round 3
// baseline (164.377 us; speedup 1.0000x reference)
//
#include <hip/hip_runtime.h>
#include <hip/hip_bf16.h>

// MultiScaleSparseSelfAttention, algebraically reduced:
//  - roll acts on (head, flatN) axes; softmax is shift-invariant over keys
//  - sum over dw collapses to P_{h,g} @ Wsum_u, Wsum = sum of v rows at {-4,-2,0,2,4}
//  - dh=+2 and dh=-2 identical (mod 4) -> weight 2
// 25 attentions/head -> 4 attentions/head.
// R2: split-K (KS chunks) for occupancy, no barriers, bf16 pre-convert,
//     unnormalized pv/ds partials folded in reduce.
// R3: FIX grid size for attn_k (tasks = 1024*KS blocks, not 512*KS — s bit
//     was never reached, scale-1 output was poison).

typedef __bf16 bf16x8 __attribute__((ext_vector_type(8)));
typedef float f32x4 __attribute__((ext_vector_type(4)));

#define MFMA16(A,B,C) __builtin_amdgcn_mfma_f32_16x16x32_bf16(A,B,C,0,0,0)

__device__ __forceinline__ bf16x8 ld8(const __bf16* p){ return *reinterpret_cast<const bf16x8*>(p); }

struct ProjArgs { const float* W[6]; const float* Bz[6]; };

// ---------------- f32 -> bf16 pre-convert: x (2x2048x256) + W (6x256x256) ----
// grid 704 x 256: 180224 groups of 8 floats
__global__ __launch_bounds__(256) void cvt_k(const float* __restrict__ x0,
                                             const float* __restrict__ x1,
                                             ProjArgs args,
                                             __bf16* __restrict__ Xb,
                                             __bf16* __restrict__ Wb)
{
    int g = blockIdx.x*256 + threadIdx.x;
    const float* src; __bf16* dst;
    if (g < 65536)      { src = x0 + (size_t)g*8;           dst = Xb + (size_t)g*8; }
    else if (g < 131072){ src = x1 + (size_t)(g-65536)*8;   dst = Xb + (size_t)g*8; }
    else {
        int gw = g - 131072;
        src = args.W[gw >> 13] + (size_t)(gw & 8191)*8;
        dst = Wb + (size_t)gw*8;
    }
    f32x4 a = *reinterpret_cast<const f32x4*>(src);
    f32x4 b = *reinterpret_cast<const f32x4*>(src+4);
    bf16x8 o;
    #pragma unroll
    for (int j=0;j<4;j++){ o[j] = (__bf16)a[j]; o[4+j] = (__bf16)b[j]; }
    *reinterpret_cast<bf16x8*>(dst) = o;
}

// ---------------- projection: Q,K,V bf16 [s][b][h][n][d] ----------------
// grid 768 = 64 rowgroups(64 rows) x 12 colgroups(64 of 768 concat q|k|v cols)
__global__ __launch_bounds__(256) void proj_k(const __bf16* __restrict__ Xb,
                                              const __bf16* __restrict__ Wb,
                                              ProjArgs args,
                                              __bf16* __restrict__ Qb,
                                              __bf16* __restrict__ Kb,
                                              __bf16* __restrict__ Vb)
{
    int bid = blockIdx.x;
    int cg = bid % 12, rg = bid / 12;
    int tid = threadIdx.x, wv = tid >> 6, l = tid & 63;
    int lr = l & 15, lg = l >> 4;
    int s = rg >> 5;                       // 2048 rows per scale
    const __bf16* Xs = Xb + (size_t)s*2048*256;
    int p = cg >> 2;                       // 0=q 1=k 2=v
    const __bf16* Wp = Wb + (size_t)(s*3+p)*65536;
    const float* bp = args.Bz[s*3 + p];
    int rowbase = rg*64 + wv*16;
    int colbase = (cg & 3)*64;

    f32x4 acc[4];
    #pragma unroll
    for (int t=0;t<4;t++) acc[t] = f32x4{0.f,0.f,0.f,0.f};

    int arow = (rowbase + lr) & 2047;      // row within [B*N] for this scale
    #pragma unroll
    for (int kk=0; kk<8; kk++){
        int ci = kk*32 + lg*8;
        bf16x8 af = ld8(Xs + (size_t)arow*256 + ci);
        #pragma unroll
        for (int ct=0; ct<4; ct++){
            int co = colbase + ct*16 + lr;
            bf16x8 bfv = ld8(Wp + (size_t)co*256 + ci);
            acc[ct] = MFMA16(af, bfv, acc[ct]);
        }
    }
    __bf16* dst = (p==0) ? Qb : (p==1) ? Kb : Vb;
    #pragma unroll
    for (int ct=0; ct<4; ct++){
        int co = colbase + ct*16 + lr;
        float bias = bp[co];
        int h = co >> 6, d = co & 63;
        #pragma unroll
        for (int i=0;i<4;i++){
            int gr = rowbase + lg*4 + i;
            int b = (gr >> 10) & 1, n = gr & 1023;
            size_t idx = ((((size_t)s*2 + b)*4 + h)*1024 + n)*64 + d;
            dst[idx] = (__bf16)(acc[ct][i] + bias);
        }
    }
}

// ------------- smoothed V, transposed: WT[s][b][u][d][n] bf16 -------------
// grid 256 = 16 sbu x 16 n-tiles(64)
__global__ __launch_bounds__(256) void smooth_k(const __bf16* __restrict__ Vb,
                                                __bf16* __restrict__ WT)
{
    __shared__ __bf16 Vt[72][66];          // stride 66 -> conflict-free col reads
    int bid = blockIdx.x;
    int sbu = bid >> 4, n0 = (bid & 15)*64;
    int tid = threadIdx.x;
    const __bf16* Vs = Vb + (size_t)sbu*1024*64;
    for (int idx = tid; idx < 576; idx += 256){
        int row = idx >> 3, ch = idx & 7;
        int n = (n0 - 4 + row) & 1023;     // circular
        bf16x8 v = ld8(Vs + (size_t)n*64 + ch*8);
        #pragma unroll
        for (int j=0;j<8;j++) Vt[row][ch*8+j] = v[j];
    }
    __syncthreads();
    int w = tid >> 6, l = tid & 63;
    __bf16* dst = WT + (size_t)sbu*64*1024;
    #pragma unroll
    for (int it=0; it<16; it++){
        int d = it*4 + w;
        float sum = 0.f;
        #pragma unroll
        for (int j=0;j<5;j++) sum += (float)Vt[l + j*2][d];   // n-4..n+4 step 2
        dst[(size_t)d*1024 + n0 + l] = (__bf16)sum;
    }
}

// ---------------- attention: wave task = (s,b,h,dhi,kchunk,16-row q tile) ---
// grid 1024*KS x 256thr (4 independent waves, no barriers).
// Writes unnormalized pv partials [slot][b][n][h*64+d] and ds [slot][b][h][n],
// slot = (s*4+dhi)*KS + kc.
__global__ __launch_bounds__(256) void attn_k(const __bf16* __restrict__ Qb,
                                              const __bf16* __restrict__ Kb,
                                              const __bf16* __restrict__ WT,
                                              float* __restrict__ pvp,
                                              float* __restrict__ dsp,
                                              int KS, int kslog, int kpc)
{
    int tid = threadIdx.x, wv = tid>>6, l = tid&63, lr = l&15, lg = l>>4;
    int t = blockIdx.x*4 + wv;
    int qt = t & 63; int r = t >> 6;
    int kc = r & (KS-1); r >>= kslog;
    int dhi = r & 3, h = (r>>2)&3, b = (r>>4)&1, s = (r>>5)&1;
    int dhv = (dhi==2) ? -1 : (dhi==3 ? 2 : dhi);   // {0,1,-1,2}
    int g = (h - dhv + 4) & 3;                      // K head
    int u = (h + dhv + 4) & 3;                      // V head
    int sb = s*2 + b;
    const __bf16* Qw = Qb + (((size_t)sb*4 + h)*1024 + qt*16)*64;
    const __bf16* Kg = Kb + ((size_t)sb*4 + g)*1024*64;
    const __bf16* Wu = WT + ((size_t)sb*4 + u)*64*1024;
    bf16x8 qa0 = ld8(Qw + lr*64 + lg*8);
    bf16x8 qa1 = ld8(Qw + lr*64 + 32 + lg*8);

    __shared__ alignas(16) __bf16 Plds[4][16][40];  // per-wave region
    __bf16* Pw = &Plds[wv][0][0];

    const f32x4 z = {0.f,0.f,0.f,0.f};
    f32x4 pv[4] = {z,z,z,z};
    float ds[4] = {0.f,0.f,0.f,0.f};
    const float c2 = 0.09016844f;                   // (1/16)*log2(e)

    int kbeg = kc * kpc, kend = kbeg + kpc;
    #pragma unroll 2
    for (int kt=kbeg; kt<kend; kt+=32){
        const __bf16* k0 = Kg + (size_t)(kt + lr)*64 + lg*8;
        bf16x8 kf00 = ld8(k0),        kf01 = ld8(k0 + 32);
        bf16x8 kf10 = ld8(k0 + 1024), kf11 = ld8(k0 + 1056);  // +16 key rows
        bf16x8 wb0 = ld8(Wu + (size_t)(lr)*1024      + kt + lg*8);
        bf16x8 wb1 = ld8(Wu + (size_t)(16+lr)*1024   + kt + lg*8);
        bf16x8 wb2 = ld8(Wu + (size_t)(32+lr)*1024   + kt + lg*8);
        bf16x8 wb3 = ld8(Wu + (size_t)(48+lr)*1024   + kt + lg*8);
        f32x4 s0 = MFMA16(qa0, kf00, z); s0 = MFMA16(qa1, kf01, s0);
        f32x4 s1 = MFMA16(qa0, kf10, z); s1 = MFMA16(qa1, kf11, s1);
        #pragma unroll
        for (int i=0;i<4;i++){
            float e0 = __builtin_amdgcn_exp2f(s0[i]*c2);
            float e1 = __builtin_amdgcn_exp2f(s1[i]*c2);
            ds[i] += e0 + e1;
            Pw[(lg*4+i)*40 + lr]      = (__bf16)e0;   // P[qrow][key]
            Pw[(lg*4+i)*40 + 16 + lr] = (__bf16)e1;
        }
        bf16x8 pa = *reinterpret_cast<const bf16x8*>(Pw + lr*40 + lg*8);
        pv[0] = MFMA16(pa, wb0, pv[0]);
        pv[1] = MFMA16(pa, wb1, pv[1]);
        pv[2] = MFMA16(pa, wb2, pv[2]);
        pv[3] = MFMA16(pa, wb3, pv[3]);
    }
    #pragma unroll
    for (int i=0;i<4;i++){
        #pragma unroll
        for (int m=1;m<16;m<<=1) ds[i] += __shfl_xor(ds[i], m, 64);
    }
    int slot = (s*4 + dhi)*KS + kc;
    float* pp = pvp + (size_t)slot*524288;
    #pragma unroll
    for (int i=0;i<4;i++){
        int n = qt*16 + lg*4 + i;
        float* row = pp + ((size_t)b*1024 + n)*256 + h*64;
        #pragma unroll
        for (int dt=0; dt<4; dt++) row[dt*16 + lr] = pv[dt][i];
    }
    if (lr == 0){
        #pragma unroll
        for (int i=0;i<4;i++)
            dsp[(size_t)slot*8192 + ((size_t)b*4+h)*1024 + qt*16 + lg*4 + i] = ds[i];
    }
}

// ------- reduce: out[b][n][c] = sum_{s,dhi} wgt/DS * sum_kc pv ------------
__global__ __launch_bounds__(256) void reduce_k(const f32x4* __restrict__ pvp,
                                                const float* __restrict__ dsp,
                                                f32x4* __restrict__ out, int KS)
{
    int idx = blockIdx.x*256 + threadIdx.x;        // 131072 f32x4
    int c4 = idx & 63, bn = idx >> 6;
    int h = c4 >> 4;
    f32x4 acc = {0.f,0.f,0.f,0.f};
    for (int s4=0; s4<8; s4++){
        float wgt = ((s4&3)==3) ? 2.f : 1.f;
        f32x4 sum = {0.f,0.f,0.f,0.f};
        float DS = 0.f;
        for (int kc=0; kc<KS; kc++){
            int slot = s4*KS + kc;
            sum += pvp[(size_t)slot*131072 + (size_t)bn*64 + c4];
            DS  += dsp[(size_t)slot*8192 + (size_t)(bn>>10)*4096 + (size_t)h*1024 + (bn & 1023)];
        }
        acc += sum * (wgt / DS);
    }
    out[idx] = acc;
}

extern "C" void kernel_launch(void* const* d_in, const int* in_sizes, int n_in,
                              void* d_out, int out_size, void* d_ws, size_t ws_size,
                              hipStream_t stream)
{
    const float* x0 = (const float*)d_in[0];
    const float* x1 = (const float*)d_in[1];
    ProjArgs pa;
    for (int s=0;s<2;s++) for (int p=0;p<3;p++){
        pa.W[s*3+p]  = (const float*)d_in[2 + s*6 + p*2];
        pa.Bz[s*3+p] = (const float*)d_in[3 + s*6 + p*2];
    }
    char* wsb = (char*)d_ws;
    __bf16* Qb = (__bf16*)(wsb);                 // 2 MB
    __bf16* Kb = (__bf16*)(wsb + (2u<<20));      // 2 MB
    __bf16* Vb = (__bf16*)(wsb + (4u<<20));      // 2 MB
    __bf16* WT = (__bf16*)(wsb + (6u<<20));      // 2 MB
    __bf16* Xb = (__bf16*)(wsb + (8u<<20));      // 2 MB  (bf16 x)
    __bf16* Wb = (__bf16*)(wsb + (10u<<20));     // 0.75 MB (bf16 weights)
    char*   pvb = wsb + (11u<<20);

    // pick split-K factor by available workspace
    size_t base = 11u<<20;
    int KS = 1, kslog = 0;
    if (ws_size >= base + 4*(16u<<20) + 4*(256u<<10)) { KS = 4; kslog = 2; }
    else if (ws_size >= base + 2*(16u<<20) + 2*(256u<<10)) { KS = 2; kslog = 1; }
    float* pvp = (float*)pvb;                    // KS*16 MB
    float* dsp = (float*)(pvb + (size_t)KS*(16u<<20)); // KS*256 KB
    int kpc = 1024 / KS;

    cvt_k<<<704, 256, 0, stream>>>(x0, x1, pa, Xb, Wb);
    proj_k<<<768, 256, 0, stream>>>(Xb, Wb, pa, Qb, Kb, Vb);
    smooth_k<<<256, 256, 0, stream>>>(Vb, WT);
    attn_k<<<1024*KS, 256, 0, stream>>>(Qb, Kb, WT, pvp, dsp, KS, kslog, kpc);
    reduce_k<<<512, 256, 0, stream>>>((const f32x4*)pvp, dsp, (f32x4*)d_out, KS);
}

// Round 4
// 75.379 us; speedup vs baseline: 2.1807x; 2.1807x over previous
//
#include <hip/hip_runtime.h>
#include <hip/hip_bf16.h>

// MultiScaleSparseSelfAttention, algebraically reduced:
//  - roll acts on (head, flatN) axes; softmax is shift-invariant over keys
//  - sum over dw collapses to P_{h,g} @ Wsum_u, Wsum = sum of v rows at {-4,-2,0,2,4}
//  - dh=+2 and dh=-2 identical (mod 4) -> weight 2
// R3: split-K KS=4, no barriers in attn, f32 pv/ds partials + reduce.
// R4: FRAGMENT-CONTIGUOUS layouts. Every ld8 in proj/attn now reads 1KB
//     contiguous (was 16x64B gather => VMEM request-rate bound at 8.3TB/s).
//     Fragment order (16x32 subtile): elem(n,d) at ((d>>3)&3)*128+(n&15)*8+(d&7),
//     i.e. lane l holds row l&15, cols (l>>4)*8..+7  == MFMA A/B fragment.
//     Softmax scale*log2e folded into Q at projection.

typedef __bf16 bf16x8 __attribute__((ext_vector_type(8)));
typedef float f32x4 __attribute__((ext_vector_type(4)));

#define MFMA16(A,B,C) __builtin_amdgcn_mfma_f32_16x16x32_bf16(A,B,C,0,0,0)

__device__ __forceinline__ bf16x8 ld8(const __bf16* p){ return *reinterpret_cast<const bf16x8*>(p); }

struct ProjArgs { const float* W[6]; const float* Bz[6]; };

// ---- cvt: f32 -> bf16 in FRAGMENT order. X: 2x(2048x256), W: 6x(256x256) ----
// grid 704x256 = 180224 groups of 8 elements (each group = one row-segment).
__global__ __launch_bounds__(256) void cvt_k(const float* __restrict__ x0,
                                             const float* __restrict__ x1,
                                             ProjArgs args,
                                             __bf16* __restrict__ Xb,
                                             __bf16* __restrict__ Wb)
{
    int g = blockIdx.x*256 + threadIdx.x;
    const float* src; __bf16* dst;
    if (g < 131072){                           // X part: s = g>>16
        int s = g >> 16;
        int E = (g & 65535)*8;                 // element offset within scale
        int blk = E >> 9, lane8 = (E >> 3) & 63;
        int row = (blk>>3)*16 + (lane8 & 15);
        int ci  = (blk&7)*32 + (lane8>>4)*8;
        src = (s ? x1 : x0) + (size_t)row*256 + ci;
        dst = Xb + (size_t)s*524288 + E;
    } else {
        int gw = g - 131072;                   // W part: sp = gw>>13
        int sp = gw >> 13;
        int E = (gw & 8191)*8;
        int blk = E >> 9, lane8 = (E >> 3) & 63;
        int co = (blk>>3)*16 + (lane8 & 15);
        int ci = (blk&7)*32 + (lane8>>4)*8;
        src = args.W[sp] + (size_t)co*256 + ci;
        dst = Wb + (size_t)sp*65536 + E;
    }
    f32x4 a = *reinterpret_cast<const f32x4*>(src);
    f32x4 b = *reinterpret_cast<const f32x4*>(src+4);
    bf16x8 o;
    #pragma unroll
    for (int j=0;j<4;j++){ o[j] = (__bf16)a[j]; o[4+j] = (__bf16)b[j]; }
    *reinterpret_cast<bf16x8*>(dst) = o;
}

// ---------------- projection ----------------
// Q,K out in fragment order [sb][h] (65536 elems each); V natural [sb][h][n][d].
// grid 768 = 64 rowgroups(64 rows) x 12 colgroups(64 of 768 concat q|k|v cols)
__global__ __launch_bounds__(256) void proj_k(const __bf16* __restrict__ Xb,
                                              const __bf16* __restrict__ Wb,
                                              ProjArgs args,
                                              __bf16* __restrict__ Qb,
                                              __bf16* __restrict__ Kb,
                                              __bf16* __restrict__ Vb)
{
    int bid = blockIdx.x;
    int cg = bid % 12, rg = bid / 12;
    int tid = threadIdx.x, wv = tid >> 6, l = tid & 63;
    int lr = l & 15, lg = l >> 4;
    int s = rg >> 5;
    const __bf16* Xf = Xb + (size_t)s*524288;
    int p = cg >> 2;                       // 0=q 1=k 2=v
    const __bf16* Wf = Wb + (size_t)(s*3+p)*65536;
    const float* bp = args.Bz[s*3 + p];
    int rowbase = rg*64 + wv*16;           // global row (0..4095), mult of 16
    int colbase = (cg & 3)*64;
    int rowblk = ((rg & 31)*4 + wv);       // 16-row block within scale

    f32x4 acc[4];
    #pragma unroll
    for (int t=0;t<4;t++) acc[t] = f32x4{0.f,0.f,0.f,0.f};

    #pragma unroll
    for (int kk=0; kk<8; kk++){
        bf16x8 af = ld8(Xf + (size_t)(rowblk*8 + kk)*512 + l*8);
        #pragma unroll
        for (int ct=0; ct<4; ct++){
            bf16x8 bfv = ld8(Wf + (size_t)(((cg&3)*4 + ct)*8 + kk)*512 + l*8);
            acc[ct] = MFMA16(af, bfv, acc[ct]);
        }
    }
    if (p < 2){
        __bf16* dst = (p==0) ? Qb : Kb;
        float qs = (p==0) ? 0.09016844136f : 1.0f;   // (1/16)*log2(e) folded into Q
        #pragma unroll
        for (int ct=0; ct<4; ct++){
            int co = colbase + ct*16 + lr;
            float bias = bp[co];
            int h = co >> 6, d = co & 63;
            #pragma unroll
            for (int i=0;i<4;i++){
                int gr = rowbase + lg*4 + i;
                int b = (gr >> 10) & 1, n = gr & 1023;
                size_t base = ((size_t)(s*2+b)*4 + h)*65536;
                size_t off = (size_t)(n>>4)*1024 + (size_t)(d>>5)*512
                           + ((d>>3)&3)*128 + (n&15)*8 + (d&7);
                dst[base + off] = (__bf16)((acc[ct][i] + bias)*qs);
            }
        }
    } else {
        #pragma unroll
        for (int ct=0; ct<4; ct++){
            int co = colbase + ct*16 + lr;
            float bias = bp[co];
            int h = co >> 6, d = co & 63;
            #pragma unroll
            for (int i=0;i<4;i++){
                int gr = rowbase + lg*4 + i;
                int b = (gr >> 10) & 1, n = gr & 1023;
                size_t idx = ((((size_t)s*2 + b)*4 + h)*1024 + n)*64 + d;
                Vb[idx] = (__bf16)(acc[ct][i] + bias);
            }
        }
    }
}

// ------ smoothed V^T in fragment order: WT[sbu] 65536 elems ------
// fragment (B over keys): elem(d,m) at (d>>4)*16384 + (m>>5)*512
//                                   + ((m>>3)&3)*128 + (d&15)*8 + (m&7)
// grid 256 = 16 sbu x 16 n-tiles(64)
__global__ __launch_bounds__(256) void smooth_k(const __bf16* __restrict__ Vb,
                                                __bf16* __restrict__ WT)
{
    __shared__ __bf16 Vt[72][66];
    int bid = blockIdx.x;
    int sbu = bid >> 4, n0 = (bid & 15)*64;
    int tid = threadIdx.x;
    const __bf16* Vs = Vb + (size_t)sbu*65536;
    for (int idx = tid; idx < 576; idx += 256){
        int row = idx >> 3, ch = idx & 7;
        int n = (n0 - 4 + row) & 1023;
        bf16x8 v = ld8(Vs + (size_t)n*64 + ch*8);
        #pragma unroll
        for (int j=0;j<8;j++) Vt[row][ch*8+j] = v[j];
    }
    __syncthreads();
    int w = tid >> 6, l = tid & 63;
    __bf16* dst = WT + (size_t)sbu*65536;
    int m = n0 + l;
    #pragma unroll
    for (int it=0; it<16; it++){
        int d = it*4 + w;
        float sum = 0.f;
        #pragma unroll
        for (int j=0;j<5;j++) sum += (float)Vt[l + j*2][d];
        dst[(size_t)(d>>4)*16384 + (size_t)(m>>5)*512
            + ((m>>3)&3)*128 + (d&15)*8 + (m&7)] = (__bf16)sum;
    }
}

// ---------------- attention: wave task = (s,b,h,dhi,kchunk,16-row q tile) ---
// grid 1024*KS x 256thr (4 independent waves/block share the K/WT stream).
// All global loads 1KB contiguous (fragment order).
__global__ __launch_bounds__(256) void attn_k(const __bf16* __restrict__ Qb,
                                              const __bf16* __restrict__ Kb,
                                              const __bf16* __restrict__ WT,
                                              float* __restrict__ pvp,
                                              float* __restrict__ dsp,
                                              int KS, int kslog, int kpc)
{
    int tid = threadIdx.x, wv = tid>>6, l = tid&63, lr = l&15, lg = l>>4;
    int t = blockIdx.x*4 + wv;
    int qt = t & 63; int r = t >> 6;
    int kc = r & (KS-1); r >>= kslog;
    int dhi = r & 3, h = (r>>2)&3, b = (r>>4)&1, s = (r>>5)&1;
    int dhv = (dhi==2) ? -1 : (dhi==3 ? 2 : dhi);   // {0,1,-1,2}
    int g = (h - dhv + 4) & 3;                      // K head
    int u = (h + dhv + 4) & 3;                      // V head
    int sb = s*2 + b;
    const __bf16* Qw = Qb + ((size_t)(sb*4 + h))*65536 + (size_t)qt*1024;
    const __bf16* Kg = Kb + ((size_t)(sb*4 + g))*65536;
    const __bf16* Wu = WT + ((size_t)(sb*4 + u))*65536;
    bf16x8 qa0 = ld8(Qw + l*8);
    bf16x8 qa1 = ld8(Qw + 512 + l*8);

    __shared__ alignas(16) __bf16 Plds[4][16][40];  // per-wave region
    __bf16* Pw = &Plds[wv][0][0];

    const f32x4 z = {0.f,0.f,0.f,0.f};
    f32x4 pv[4] = {z,z,z,z};
    float ds[4] = {0.f,0.f,0.f,0.f};

    int kbeg = kc * kpc, kend = kbeg + kpc;
    #pragma unroll 2
    for (int kt=kbeg; kt<kend; kt+=32){
        const __bf16* k0 = Kg + (size_t)(kt>>4)*1024 + l*8;
        bf16x8 kf00 = ld8(k0),        kf01 = ld8(k0 + 512);
        bf16x8 kf10 = ld8(k0 + 1024), kf11 = ld8(k0 + 1536);
        const __bf16* w0 = Wu + (size_t)(kt>>5)*512 + l*8;
        bf16x8 wb0 = ld8(w0);
        bf16x8 wb1 = ld8(w0 + 16384);
        bf16x8 wb2 = ld8(w0 + 32768);
        bf16x8 wb3 = ld8(w0 + 49152);
        f32x4 s0 = MFMA16(qa0, kf00, z); s0 = MFMA16(qa1, kf01, s0);
        f32x4 s1 = MFMA16(qa0, kf10, z); s1 = MFMA16(qa1, kf11, s1);
        #pragma unroll
        for (int i=0;i<4;i++){
            float e0 = __builtin_amdgcn_exp2f(s0[i]);   // scale folded into Q
            float e1 = __builtin_amdgcn_exp2f(s1[i]);
            ds[i] += e0 + e1;
            Pw[(lg*4+i)*40 + lr]      = (__bf16)e0;
            Pw[(lg*4+i)*40 + 16 + lr] = (__bf16)e1;
        }
        bf16x8 pa = *reinterpret_cast<const bf16x8*>(Pw + lr*40 + lg*8);
        pv[0] = MFMA16(pa, wb0, pv[0]);
        pv[1] = MFMA16(pa, wb1, pv[1]);
        pv[2] = MFMA16(pa, wb2, pv[2]);
        pv[3] = MFMA16(pa, wb3, pv[3]);
    }
    #pragma unroll
    for (int i=0;i<4;i++){
        #pragma unroll
        for (int m=1;m<16;m<<=1) ds[i] += __shfl_xor(ds[i], m, 64);
    }
    int slot = (s*4 + dhi)*KS + kc;
    float* pp = pvp + (size_t)slot*524288;
    #pragma unroll
    for (int i=0;i<4;i++){
        int n = qt*16 + lg*4 + i;
        float* row = pp + ((size_t)b*1024 + n)*256 + h*64;
        #pragma unroll
        for (int dt=0; dt<4; dt++) row[dt*16 + lr] = pv[dt][i];
    }
    if (lr == 0){
        #pragma unroll
        for (int i=0;i<4;i++)
            dsp[(size_t)slot*8192 + ((size_t)b*4+h)*1024 + qt*16 + lg*4 + i] = ds[i];
    }
}

// ------- reduce: out[b][n][c] = sum_{s,dhi} wgt/DS * sum_kc pv ------------
__global__ __launch_bounds__(256) void reduce_k(const f32x4* __restrict__ pvp,
                                                const float* __restrict__ dsp,
                                                f32x4* __restrict__ out, int KS)
{
    int idx = blockIdx.x*256 + threadIdx.x;        // 131072 f32x4
    int c4 = idx & 63, bn = idx >> 6;
    int h = c4 >> 4;
    f32x4 acc = {0.f,0.f,0.f,0.f};
    for (int s4=0; s4<8; s4++){
        float wgt = ((s4&3)==3) ? 2.f : 1.f;
        f32x4 sum = {0.f,0.f,0.f,0.f};
        float DS = 0.f;
        for (int kc=0; kc<KS; kc++){
            int slot = s4*KS + kc;
            sum += pvp[(size_t)slot*131072 + (size_t)bn*64 + c4];
            DS  += dsp[(size_t)slot*8192 + (size_t)(bn>>10)*4096 + (size_t)h*1024 + (bn & 1023)];
        }
        acc += sum * (wgt / DS);
    }
    out[idx] = acc;
}

extern "C" void kernel_launch(void* const* d_in, const int* in_sizes, int n_in,
                              void* d_out, int out_size, void* d_ws, size_t ws_size,
                              hipStream_t stream)
{
    const float* x0 = (const float*)d_in[0];
    const float* x1 = (const float*)d_in[1];
    ProjArgs pa;
    for (int s=0;s<2;s++) for (int p=0;p<3;p++){
        pa.W[s*3+p]  = (const float*)d_in[2 + s*6 + p*2];
        pa.Bz[s*3+p] = (const float*)d_in[3 + s*6 + p*2];
    }
    char* wsb = (char*)d_ws;
    __bf16* Qb = (__bf16*)(wsb);                 // 2 MB (fragment order)
    __bf16* Kb = (__bf16*)(wsb + (2u<<20));      // 2 MB (fragment order)
    __bf16* Vb = (__bf16*)(wsb + (4u<<20));      // 2 MB (natural)
    __bf16* WT = (__bf16*)(wsb + (6u<<20));      // 2 MB (fragment order)
    __bf16* Xb = (__bf16*)(wsb + (8u<<20));      // 2 MB (fragment order)
    __bf16* Wb = (__bf16*)(wsb + (10u<<20));     // 0.75 MB (fragment order)
    char*   pvb = wsb + (11u<<20);

    size_t base = 11u<<20;
    int KS = 1, kslog = 0;
    if (ws_size >= base + 4*(16u<<20) + 4*(256u<<10)) { KS = 4; kslog = 2; }
    else if (ws_size >= base + 2*(16u<<20) + 2*(256u<<10)) { KS = 2; kslog = 1; }
    float* pvp = (float*)pvb;                    // KS*16 MB
    float* dsp = (float*)(pvb + (size_t)KS*(16u<<20)); // KS*256 KB
    int kpc = 1024 / KS;

    cvt_k<<<704, 256, 0, stream>>>(x0, x1, pa, Xb, Wb);
    proj_k<<<768, 256, 0, stream>>>(Xb, Wb, pa, Qb, Kb, Vb);
    smooth_k<<<256, 256, 0, stream>>>(Vb, WT);
    attn_k<<<1024*KS, 256, 0, stream>>>(Qb, Kb, WT, pvp, dsp, KS, kslog, kpc);
    reduce_k<<<512, 256, 0, stream>>>((const f32x4*)pvp, dsp, (f32x4*)d_out, KS);
}

// Round 5
// 65.715 us; speedup vs baseline: 2.5014x; 1.1471x over previous
//
#include <hip/hip_runtime.h>
#include <hip/hip_bf16.h>

// MultiScaleSparseSelfAttention, algebraically reduced:
//  - roll acts on (head, flatN) axes; softmax is shift-invariant over keys
//  - sum over dw collapses to P_{h,g} @ Wsum_u, Wsum = sum of v rows at {-4,-2,0,2,4}
//  - dh=+2 and dh=-2 identical (mod 4) -> weight 2
// R4: fragment-contiguous layouts (1KB per wave load), scale folded into Q.
// R5: attn 32 q-rows/wave, 4 waves/block share one K/W stream (barrier-synced
//     for L1 reuse) -> ~4-8x less L2 traffic; pvp partials in bf16 (halves
//     attn HBM writes + reduce reads).

typedef __bf16 bf16x8 __attribute__((ext_vector_type(8)));
typedef float f32x4 __attribute__((ext_vector_type(4)));

#define MFMA16(A,B,C) __builtin_amdgcn_mfma_f32_16x16x32_bf16(A,B,C,0,0,0)

__device__ __forceinline__ bf16x8 ld8(const __bf16* p){ return *reinterpret_cast<const bf16x8*>(p); }

struct ProjArgs { const float* W[6]; const float* Bz[6]; };

// ---- cvt: f32 -> bf16 in FRAGMENT order. X: 2x(2048x256), W: 6x(256x256) ----
__global__ __launch_bounds__(256) void cvt_k(const float* __restrict__ x0,
                                             const float* __restrict__ x1,
                                             ProjArgs args,
                                             __bf16* __restrict__ Xb,
                                             __bf16* __restrict__ Wb)
{
    int g = blockIdx.x*256 + threadIdx.x;
    const float* src; __bf16* dst;
    if (g < 131072){                           // X part: s = g>>16
        int s = g >> 16;
        int E = (g & 65535)*8;                 // element offset within scale
        int blk = E >> 9, lane8 = (E >> 3) & 63;
        int row = (blk>>3)*16 + (lane8 & 15);
        int ci  = (blk&7)*32 + (lane8>>4)*8;
        src = (s ? x1 : x0) + (size_t)row*256 + ci;
        dst = Xb + (size_t)s*524288 + E;
    } else {
        int gw = g - 131072;                   // W part: sp = gw>>13
        int sp = gw >> 13;
        int E = (gw & 8191)*8;
        int blk = E >> 9, lane8 = (E >> 3) & 63;
        int co = (blk>>3)*16 + (lane8 & 15);
        int ci = (blk&7)*32 + (lane8>>4)*8;
        src = args.W[sp] + (size_t)co*256 + ci;
        dst = Wb + (size_t)sp*65536 + E;
    }
    f32x4 a = *reinterpret_cast<const f32x4*>(src);
    f32x4 b = *reinterpret_cast<const f32x4*>(src+4);
    bf16x8 o;
    #pragma unroll
    for (int j=0;j<4;j++){ o[j] = (__bf16)a[j]; o[4+j] = (__bf16)b[j]; }
    *reinterpret_cast<bf16x8*>(dst) = o;
}

// ---------------- projection ----------------
__global__ __launch_bounds__(256) void proj_k(const __bf16* __restrict__ Xb,
                                              const __bf16* __restrict__ Wb,
                                              ProjArgs args,
                                              __bf16* __restrict__ Qb,
                                              __bf16* __restrict__ Kb,
                                              __bf16* __restrict__ Vb)
{
    int bid = blockIdx.x;
    int cg = bid % 12, rg = bid / 12;
    int tid = threadIdx.x, wv = tid >> 6, l = tid & 63;
    int lr = l & 15, lg = l >> 4;
    int s = rg >> 5;
    const __bf16* Xf = Xb + (size_t)s*524288;
    int p = cg >> 2;                       // 0=q 1=k 2=v
    const __bf16* Wf = Wb + (size_t)(s*3+p)*65536;
    const float* bp = args.Bz[s*3 + p];
    int rowbase = rg*64 + wv*16;
    int colbase = (cg & 3)*64;
    int rowblk = ((rg & 31)*4 + wv);

    f32x4 acc[4];
    #pragma unroll
    for (int t=0;t<4;t++) acc[t] = f32x4{0.f,0.f,0.f,0.f};

    #pragma unroll
    for (int kk=0; kk<8; kk++){
        bf16x8 af = ld8(Xf + (size_t)(rowblk*8 + kk)*512 + l*8);
        #pragma unroll
        for (int ct=0; ct<4; ct++){
            bf16x8 bfv = ld8(Wf + (size_t)(((cg&3)*4 + ct)*8 + kk)*512 + l*8);
            acc[ct] = MFMA16(af, bfv, acc[ct]);
        }
    }
    if (p < 2){
        __bf16* dst = (p==0) ? Qb : Kb;
        float qs = (p==0) ? 0.09016844136f : 1.0f;   // (1/16)*log2(e) into Q
        #pragma unroll
        for (int ct=0; ct<4; ct++){
            int co = colbase + ct*16 + lr;
            float bias = bp[co];
            int h = co >> 6, d = co & 63;
            #pragma unroll
            for (int i=0;i<4;i++){
                int gr = rowbase + lg*4 + i;
                int b = (gr >> 10) & 1, n = gr & 1023;
                size_t base = ((size_t)(s*2+b)*4 + h)*65536;
                size_t off = (size_t)(n>>4)*1024 + (size_t)(d>>5)*512
                           + ((d>>3)&3)*128 + (n&15)*8 + (d&7);
                dst[base + off] = (__bf16)((acc[ct][i] + bias)*qs);
            }
        }
    } else {
        #pragma unroll
        for (int ct=0; ct<4; ct++){
            int co = colbase + ct*16 + lr;
            float bias = bp[co];
            int h = co >> 6, d = co & 63;
            #pragma unroll
            for (int i=0;i<4;i++){
                int gr = rowbase + lg*4 + i;
                int b = (gr >> 10) & 1, n = gr & 1023;
                size_t idx = ((((size_t)s*2 + b)*4 + h)*1024 + n)*64 + d;
                Vb[idx] = (__bf16)(acc[ct][i] + bias);
            }
        }
    }
}

// ------ smoothed V^T in fragment order: WT[sbu] 65536 elems ------
__global__ __launch_bounds__(256) void smooth_k(const __bf16* __restrict__ Vb,
                                                __bf16* __restrict__ WT)
{
    __shared__ __bf16 Vt[72][66];
    int bid = blockIdx.x;
    int sbu = bid >> 4, n0 = (bid & 15)*64;
    int tid = threadIdx.x;
    const __bf16* Vs = Vb + (size_t)sbu*65536;
    for (int idx = tid; idx < 576; idx += 256){
        int row = idx >> 3, ch = idx & 7;
        int n = (n0 - 4 + row) & 1023;
        bf16x8 v = ld8(Vs + (size_t)n*64 + ch*8);
        #pragma unroll
        for (int j=0;j<8;j++) Vt[row][ch*8+j] = v[j];
    }
    __syncthreads();
    int w = tid >> 6, l = tid & 63;
    __bf16* dst = WT + (size_t)sbu*65536;
    int m = n0 + l;
    #pragma unroll
    for (int it=0; it<16; it++){
        int d = it*4 + w;
        float sum = 0.f;
        #pragma unroll
        for (int j=0;j<5;j++) sum += (float)Vt[l + j*2][d];
        dst[(size_t)(d>>4)*16384 + (size_t)(m>>5)*512
            + ((m>>3)&3)*128 + (d&15)*8 + (m&7)] = (__bf16)sum;
    }
}

// ---------------- attention ----------------
// Block task = (s,b,h,dhi,kc,qg): 4 waves x 32 q-rows = 128 rows, one shared
// K/W stream, barrier-synced per iter for L1 reuse. Outputs bf16 pv partials.
__global__ __launch_bounds__(256) void attn_k(const __bf16* __restrict__ Qb,
                                              const __bf16* __restrict__ Kb,
                                              const __bf16* __restrict__ WT,
                                              __bf16* __restrict__ pvp,
                                              float* __restrict__ dsp,
                                              int KS, int kslog, int kpc)
{
    int tid = threadIdx.x, wv = tid>>6, l = tid&63, lr = l&15, lg = l>>4;
    int t = blockIdx.x;
    int qg = t & 7; t >>= 3;
    int kc = t & (KS-1); t >>= kslog;
    int dhi = t & 3, h = (t>>2)&3, b = (t>>4)&1, s = (t>>5)&1;
    int dhv = (dhi==2) ? -1 : (dhi==3 ? 2 : dhi);   // {0,1,-1,2}
    int g = (h - dhv + 4) & 3;                      // K head
    int u = (h + dhv + 4) & 3;                      // V head
    int sb = s*2 + b;
    int nbase = qg*128 + wv*32;
    const __bf16* Qw = Qb + ((size_t)(sb*4 + h))*65536 + (size_t)(nbase>>4)*1024;
    const __bf16* Kg = Kb + ((size_t)(sb*4 + g))*65536;
    const __bf16* Wu = WT + ((size_t)(sb*4 + u))*65536;
    bf16x8 qa00 = ld8(Qw + l*8),        qa01 = ld8(Qw + 512 + l*8);
    bf16x8 qa10 = ld8(Qw + 1024 + l*8), qa11 = ld8(Qw + 1536 + l*8);

    __shared__ alignas(16) __bf16 Plds[4][32*40];   // per-wave [32 rows][40]
    __bf16* Pw = Plds[wv];

    const f32x4 z = {0.f,0.f,0.f,0.f};
    f32x4 pv[2][4];
    #pragma unroll
    for (int rb=0;rb<2;rb++)
        #pragma unroll
        for (int dt=0;dt<4;dt++) pv[rb][dt] = z;
    float ds[2][4] = {{0.f,0.f,0.f,0.f},{0.f,0.f,0.f,0.f}};

    int kbeg = kc * kpc, kend = kbeg + kpc;
    for (int kt=kbeg; kt<kend; kt+=32){
        __syncthreads();                            // converge waves -> L1 hits
        const __bf16* k0 = Kg + (size_t)(kt>>4)*1024 + l*8;
        bf16x8 kf00 = ld8(k0),        kf01 = ld8(k0 + 512);
        bf16x8 kf10 = ld8(k0 + 1024), kf11 = ld8(k0 + 1536);
        const __bf16* w0 = Wu + (size_t)(kt>>5)*512 + l*8;
        bf16x8 wb0 = ld8(w0);
        bf16x8 wb1 = ld8(w0 + 16384);
        bf16x8 wb2 = ld8(w0 + 32768);
        bf16x8 wb3 = ld8(w0 + 49152);
        f32x4 s00 = MFMA16(qa00, kf00, z); s00 = MFMA16(qa01, kf01, s00);
        f32x4 s01 = MFMA16(qa00, kf10, z); s01 = MFMA16(qa01, kf11, s01);
        f32x4 s10 = MFMA16(qa10, kf00, z); s10 = MFMA16(qa11, kf01, s10);
        f32x4 s11 = MFMA16(qa10, kf10, z); s11 = MFMA16(qa11, kf11, s11);
        #pragma unroll
        for (int i=0;i<4;i++){
            float e00 = __builtin_amdgcn_exp2f(s00[i]);
            float e01 = __builtin_amdgcn_exp2f(s01[i]);
            float e10 = __builtin_amdgcn_exp2f(s10[i]);
            float e11 = __builtin_amdgcn_exp2f(s11[i]);
            ds[0][i] += e00 + e01;
            ds[1][i] += e10 + e11;
            int r0 = (lg*4+i)*40, r1 = (16+lg*4+i)*40;
            Pw[r0 + lr]      = (__bf16)e00;
            Pw[r0 + 16 + lr] = (__bf16)e01;
            Pw[r1 + lr]      = (__bf16)e10;
            Pw[r1 + 16 + lr] = (__bf16)e11;
        }
        bf16x8 pa0 = *reinterpret_cast<const bf16x8*>(Pw + lr*40 + lg*8);
        bf16x8 pa1 = *reinterpret_cast<const bf16x8*>(Pw + (16+lr)*40 + lg*8);
        pv[0][0] = MFMA16(pa0, wb0, pv[0][0]);
        pv[0][1] = MFMA16(pa0, wb1, pv[0][1]);
        pv[0][2] = MFMA16(pa0, wb2, pv[0][2]);
        pv[0][3] = MFMA16(pa0, wb3, pv[0][3]);
        pv[1][0] = MFMA16(pa1, wb0, pv[1][0]);
        pv[1][1] = MFMA16(pa1, wb1, pv[1][1]);
        pv[1][2] = MFMA16(pa1, wb2, pv[1][2]);
        pv[1][3] = MFMA16(pa1, wb3, pv[1][3]);
    }
    #pragma unroll
    for (int rb=0;rb<2;rb++)
        #pragma unroll
        for (int i=0;i<4;i++){
            #pragma unroll
            for (int m=1;m<16;m<<=1) ds[rb][i] += __shfl_xor(ds[rb][i], m, 64);
        }
    int slot = (s*4 + dhi)*KS + kc;
    __bf16* pp = pvp + (size_t)slot*524288;
    #pragma unroll
    for (int rb=0;rb<2;rb++){
        #pragma unroll
        for (int i=0;i<4;i++){
            int n = nbase + rb*16 + lg*4 + i;
            __bf16* row = pp + ((size_t)b*1024 + n)*256 + h*64;
            #pragma unroll
            for (int dt=0; dt<4; dt++) row[dt*16 + lr] = (__bf16)pv[rb][dt][i];
        }
    }
    if (lr == 0){
        #pragma unroll
        for (int rb=0;rb<2;rb++)
            #pragma unroll
            for (int i=0;i<4;i++)
                dsp[(size_t)slot*8192 + ((size_t)b*4+h)*1024 + nbase + rb*16 + lg*4 + i] = ds[rb][i];
    }
}

// ------- reduce: out[b][n][c] = sum_{s,dhi} wgt/DS * sum_kc pv ------------
// grid 256x256: each thread 8 channels of one (b,n).
__global__ __launch_bounds__(256) void reduce_k(const __bf16* __restrict__ pvp,
                                                const float* __restrict__ dsp,
                                                float* __restrict__ out, int KS)
{
    int idx = blockIdx.x*256 + threadIdx.x;        // 0..65535
    int c8 = idx & 31, bn = idx >> 5;
    int h = c8 >> 3;
    size_t dsoff = (size_t)(bn>>10)*4096 + (size_t)h*1024 + (bn & 1023);
    float acc[8] = {0,0,0,0,0,0,0,0};
    for (int s4=0; s4<8; s4++){
        float wgt = ((s4&3)==3) ? 2.f : 1.f;
        float fsum[8] = {0,0,0,0,0,0,0,0};
        float DS = 0.f;
        for (int kc=0; kc<KS; kc++){
            int slot = s4*KS + kc;
            bf16x8 v = ld8(pvp + (size_t)slot*524288 + (size_t)bn*256 + c8*8);
            #pragma unroll
            for (int j=0;j<8;j++) fsum[j] += (float)v[j];
            DS += dsp[(size_t)slot*8192 + dsoff];
        }
        float sc = wgt / DS;
        #pragma unroll
        for (int j=0;j<8;j++) acc[j] += fsum[j]*sc;
    }
    f32x4 o0 = {acc[0],acc[1],acc[2],acc[3]};
    f32x4 o1 = {acc[4],acc[5],acc[6],acc[7]};
    *reinterpret_cast<f32x4*>(out + (size_t)idx*8)     = o0;
    *reinterpret_cast<f32x4*>(out + (size_t)idx*8 + 4) = o1;
}

extern "C" void kernel_launch(void* const* d_in, const int* in_sizes, int n_in,
                              void* d_out, int out_size, void* d_ws, size_t ws_size,
                              hipStream_t stream)
{
    const float* x0 = (const float*)d_in[0];
    const float* x1 = (const float*)d_in[1];
    ProjArgs pa;
    for (int s=0;s<2;s++) for (int p=0;p<3;p++){
        pa.W[s*3+p]  = (const float*)d_in[2 + s*6 + p*2];
        pa.Bz[s*3+p] = (const float*)d_in[3 + s*6 + p*2];
    }
    char* wsb = (char*)d_ws;
    __bf16* Qb = (__bf16*)(wsb);                 // 2 MB (fragment order)
    __bf16* Kb = (__bf16*)(wsb + (2u<<20));      // 2 MB (fragment order)
    __bf16* Vb = (__bf16*)(wsb + (4u<<20));      // 2 MB (natural)
    __bf16* WT = (__bf16*)(wsb + (6u<<20));      // 2 MB (fragment order)
    __bf16* Xb = (__bf16*)(wsb + (8u<<20));      // 2 MB (fragment order)
    __bf16* Wb = (__bf16*)(wsb + (10u<<20));     // 0.75 MB (fragment order)
    char*   pvb = wsb + (11u<<20);

    size_t base = 11u<<20;
    int KS = 1, kslog = 0;
    if (ws_size >= base + 4*(8u<<20) + 4*(256u<<10)) { KS = 4; kslog = 2; }
    else if (ws_size >= base + 2*(8u<<20) + 2*(256u<<10)) { KS = 2; kslog = 1; }
    __bf16* pvp = (__bf16*)pvb;                        // KS*8 MB (bf16)
    float*  dsp = (float*)(pvb + (size_t)KS*(8u<<20)); // KS*256 KB
    int kpc = 1024 / KS;

    cvt_k<<<704, 256, 0, stream>>>(x0, x1, pa, Xb, Wb);
    proj_k<<<768, 256, 0, stream>>>(Xb, Wb, pa, Qb, Kb, Vb);
    smooth_k<<<256, 256, 0, stream>>>(Vb, WT);
    attn_k<<<512*KS, 256, 0, stream>>>(Qb, Kb, WT, pvp, dsp, KS, kslog, kpc);
    reduce_k<<<256, 256, 0, stream>>>(pvp, dsp, (float*)d_out, KS);
}

// Round 6
// 55.028 us; speedup vs baseline: 2.9871x; 1.1942x over previous
//
#include <hip/hip_runtime.h>
#include <hip/hip_bf16.h>

// MultiScaleSparseSelfAttention, algebraically reduced:
//  - roll acts on (head, flatN) axes; softmax is shift-invariant over keys
//  - sum over dw collapses to P_{h,g} @ Wsum_u, Wsum = sum of v rows at {-4,-2,0,2,4}
//  - dh=+2 and dh=-2 identical (mod 4) -> weight 2
// R4: fragment-contiguous layouts (1KB per wave load), scale folded into Q.
// R5: 32 q-rows/wave, bf16 pv partials.
// R6: SWAPPED-OPERAND attention. S^T = mfma(K,Q) puts 8 keys per lane; after
//     exp, packing them is directly a B-fragment for O^T = mfma(Wsig, P)
//     with Wsum stored in key-permuted order sigma. No LDS / barriers /
//     shuffles in the K-loop. KS=2.

typedef __bf16 bf16x8 __attribute__((ext_vector_type(8)));
typedef __bf16 bf16x4 __attribute__((ext_vector_type(4)));
typedef float f32x4 __attribute__((ext_vector_type(4)));

#define MFMA16(A,B,C) __builtin_amdgcn_mfma_f32_16x16x32_bf16(A,B,C,0,0,0)

__device__ __forceinline__ bf16x8 ld8(const __bf16* p){ return *reinterpret_cast<const bf16x8*>(p); }

struct ProjArgs { const float* W[6]; const float* Bz[6]; };

// ---- cvt: f32 -> bf16 in FRAGMENT order. X: 2x(2048x256), W: 6x(256x256) ----
__global__ __launch_bounds__(256) void cvt_k(const float* __restrict__ x0,
                                             const float* __restrict__ x1,
                                             ProjArgs args,
                                             __bf16* __restrict__ Xb,
                                             __bf16* __restrict__ Wb)
{
    int g = blockIdx.x*256 + threadIdx.x;
    const float* src; __bf16* dst;
    if (g < 131072){                           // X part: s = g>>16
        int s = g >> 16;
        int E = (g & 65535)*8;                 // element offset within scale
        int blk = E >> 9, lane8 = (E >> 3) & 63;
        int row = (blk>>3)*16 + (lane8 & 15);
        int ci  = (blk&7)*32 + (lane8>>4)*8;
        src = (s ? x1 : x0) + (size_t)row*256 + ci;
        dst = Xb + (size_t)s*524288 + E;
    } else {
        int gw = g - 131072;                   // W part: sp = gw>>13
        int sp = gw >> 13;
        int E = (gw & 8191)*8;
        int blk = E >> 9, lane8 = (E >> 3) & 63;
        int co = (blk>>3)*16 + (lane8 & 15);
        int ci = (blk&7)*32 + (lane8>>4)*8;
        src = args.W[sp] + (size_t)co*256 + ci;
        dst = Wb + (size_t)sp*65536 + E;
    }
    f32x4 a = *reinterpret_cast<const f32x4*>(src);
    f32x4 b = *reinterpret_cast<const f32x4*>(src+4);
    bf16x8 o;
    #pragma unroll
    for (int j=0;j<4;j++){ o[j] = (__bf16)a[j]; o[4+j] = (__bf16)b[j]; }
    *reinterpret_cast<bf16x8*>(dst) = o;
}

// ---------------- projection ----------------
__global__ __launch_bounds__(256) void proj_k(const __bf16* __restrict__ Xb,
                                              const __bf16* __restrict__ Wb,
                                              ProjArgs args,
                                              __bf16* __restrict__ Qb,
                                              __bf16* __restrict__ Kb,
                                              __bf16* __restrict__ Vb)
{
    int bid = blockIdx.x;
    int cg = bid % 12, rg = bid / 12;
    int tid = threadIdx.x, wv = tid >> 6, l = tid & 63;
    int lr = l & 15, lg = l >> 4;
    int s = rg >> 5;
    const __bf16* Xf = Xb + (size_t)s*524288;
    int p = cg >> 2;                       // 0=q 1=k 2=v
    const __bf16* Wf = Wb + (size_t)(s*3+p)*65536;
    const float* bp = args.Bz[s*3 + p];
    int rowbase = rg*64 + wv*16;
    int colbase = (cg & 3)*64;
    int rowblk = ((rg & 31)*4 + wv);

    f32x4 acc[4];
    #pragma unroll
    for (int t=0;t<4;t++) acc[t] = f32x4{0.f,0.f,0.f,0.f};

    #pragma unroll
    for (int kk=0; kk<8; kk++){
        bf16x8 af = ld8(Xf + (size_t)(rowblk*8 + kk)*512 + l*8);
        #pragma unroll
        for (int ct=0; ct<4; ct++){
            bf16x8 bfv = ld8(Wf + (size_t)(((cg&3)*4 + ct)*8 + kk)*512 + l*8);
            acc[ct] = MFMA16(af, bfv, acc[ct]);
        }
    }
    if (p < 2){
        __bf16* dst = (p==0) ? Qb : Kb;
        float qs = (p==0) ? 0.09016844136f : 1.0f;   // (1/16)*log2(e) into Q
        #pragma unroll
        for (int ct=0; ct<4; ct++){
            int co = colbase + ct*16 + lr;
            float bias = bp[co];
            int h = co >> 6, d = co & 63;
            #pragma unroll
            for (int i=0;i<4;i++){
                int gr = rowbase + lg*4 + i;
                int b = (gr >> 10) & 1, n = gr & 1023;
                size_t base = ((size_t)(s*2+b)*4 + h)*65536;
                size_t off = (size_t)(n>>4)*1024 + (size_t)(d>>5)*512
                           + ((d>>3)&3)*128 + (n&15)*8 + (d&7);
                dst[base + off] = (__bf16)((acc[ct][i] + bias)*qs);
            }
        }
    } else {
        #pragma unroll
        for (int ct=0; ct<4; ct++){
            int co = colbase + ct*16 + lr;
            float bias = bp[co];
            int h = co >> 6, d = co & 63;
            #pragma unroll
            for (int i=0;i<4;i++){
                int gr = rowbase + lg*4 + i;
                int b = (gr >> 10) & 1, n = gr & 1023;
                size_t idx = ((((size_t)s*2 + b)*4 + h)*1024 + n)*64 + d;
                Vb[idx] = (__bf16)(acc[ct][i] + bias);
            }
        }
    }
}

// ------ smoothed V^T, sigma-permuted A-fragment order: Wsig[sbu] ------
// elem(d, key m): kb = m>>5, p = sigma^{-1}(m&31);
// addr = kb*2048 + (d>>4)*512 + (p>>3)*128 + (d&15)*8 + (p&7)
// sigma^{-1}: m32<16 -> (m32>>2)*8 + (m32&3); else ((m32-16)>>2)*8+4+(m32&3)
__global__ __launch_bounds__(256) void smooth_k(const __bf16* __restrict__ Vb,
                                                __bf16* __restrict__ WT)
{
    __shared__ __bf16 Vt[72][66];
    int bid = blockIdx.x;
    int sbu = bid >> 4, n0 = (bid & 15)*64;
    int tid = threadIdx.x;
    const __bf16* Vs = Vb + (size_t)sbu*65536;
    for (int idx = tid; idx < 576; idx += 256){
        int row = idx >> 3, ch = idx & 7;
        int n = (n0 - 4 + row) & 1023;
        bf16x8 v = ld8(Vs + (size_t)n*64 + ch*8);
        #pragma unroll
        for (int j=0;j<8;j++) Vt[row][ch*8+j] = v[j];
    }
    __syncthreads();
    int w = tid >> 6, l = tid & 63;
    __bf16* dst = WT + (size_t)sbu*65536;
    int m = n0 + l;
    int kb = m >> 5, m32 = m & 31;
    int p = (m32 < 16) ? ((m32>>2)*8 + (m32&3))
                       : (((m32-16)>>2)*8 + 4 + (m32&3));
    size_t pbase = (size_t)kb*2048 + (p>>3)*128 + (p&7);
    #pragma unroll
    for (int it=0; it<16; it++){
        int d = it*4 + w;
        float sum = 0.f;
        #pragma unroll
        for (int j=0;j<5;j++) sum += (float)Vt[l + j*2][d];
        dst[pbase + (size_t)(d>>4)*512 + (d&15)*8] = (__bf16)sum;
    }
}

// ---------------- attention (swapped operands, no LDS) ----------------
// Block task = (s,b,h,dhi,kc,qg): 4 waves x 32 q-rows.
// S^T = mfma(K,Q): lane (lr=qrow, lg) holds keys {4lg+i} u {16+4lg+i}.
// exp -> pack -> B-fragment; O^T = mfma(Wsig_dt, P) accumulates d-tiles.
__global__ __launch_bounds__(256) void attn_k(const __bf16* __restrict__ Qb,
                                              const __bf16* __restrict__ Kb,
                                              const __bf16* __restrict__ WT,
                                              __bf16* __restrict__ pvp,
                                              float* __restrict__ dsp,
                                              int KS, int kslog, int kpc)
{
    int tid = threadIdx.x, wv = tid>>6, l = tid&63, lr = l&15, lg = l>>4;
    int t = blockIdx.x;
    int qg = t & 7; t >>= 3;
    int kc = t & (KS-1); t >>= kslog;
    int dhi = t & 3, h = (t>>2)&3, b = (t>>4)&1, s = (t>>5)&1;
    int dhv = (dhi==2) ? -1 : (dhi==3 ? 2 : dhi);   // {0,1,-1,2}
    int g = (h - dhv + 4) & 3;                      // K head
    int u = (h + dhv + 4) & 3;                      // V head
    int sb = s*2 + b;
    int nbase = qg*128 + wv*32;
    const __bf16* Qw = Qb + ((size_t)(sb*4 + h))*65536 + (size_t)(nbase>>4)*1024;
    const __bf16* Kg = Kb + ((size_t)(sb*4 + g))*65536;
    const __bf16* Wu = WT + ((size_t)(sb*4 + u))*65536;
    bf16x8 qa0 = ld8(Qw + l*8),        qa1 = ld8(Qw + 512 + l*8);
    bf16x8 qb0 = ld8(Qw + 1024 + l*8), qb1 = ld8(Qw + 1536 + l*8);

    const f32x4 z = {0.f,0.f,0.f,0.f};
    f32x4 pvA[4] = {z,z,z,z};
    f32x4 pvB[4] = {z,z,z,z};
    float dsA = 0.f, dsB = 0.f;

    int kbeg = kc * kpc, kend = kbeg + kpc;
    for (int kt=kbeg; kt<kend; kt+=32){
        const __bf16* k0 = Kg + (size_t)(kt>>4)*1024 + l*8;
        bf16x8 kf00 = ld8(k0),        kf01 = ld8(k0 + 512);
        bf16x8 kf10 = ld8(k0 + 1024), kf11 = ld8(k0 + 1536);
        const __bf16* w0 = Wu + (size_t)(kt>>5)*2048 + l*8;
        bf16x8 wd0 = ld8(w0);
        bf16x8 wd1 = ld8(w0 + 512);
        bf16x8 wd2 = ld8(w0 + 1024);
        bf16x8 wd3 = ld8(w0 + 1536);
        // S^T blocks: rows=keys, cols=qrows
        f32x4 sA0 = MFMA16(kf00, qa0, z); sA0 = MFMA16(kf01, qa1, sA0);
        f32x4 sA1 = MFMA16(kf10, qa0, z); sA1 = MFMA16(kf11, qa1, sA1);
        f32x4 sB0 = MFMA16(kf00, qb0, z); sB0 = MFMA16(kf01, qb1, sB0);
        f32x4 sB1 = MFMA16(kf10, qb0, z); sB1 = MFMA16(kf11, qb1, sB1);
        bf16x8 paA, paB;
        #pragma unroll
        for (int i=0;i<4;i++){
            float eA0 = __builtin_amdgcn_exp2f(sA0[i]);
            float eA1 = __builtin_amdgcn_exp2f(sA1[i]);
            float eB0 = __builtin_amdgcn_exp2f(sB0[i]);
            float eB1 = __builtin_amdgcn_exp2f(sB1[i]);
            dsA += eA0 + eA1;
            dsB += eB0 + eB1;
            paA[i] = (__bf16)eA0; paA[4+i] = (__bf16)eA1;
            paB[i] = (__bf16)eB0; paB[4+i] = (__bf16)eB1;
        }
        pvA[0] = MFMA16(wd0, paA, pvA[0]);
        pvA[1] = MFMA16(wd1, paA, pvA[1]);
        pvA[2] = MFMA16(wd2, paA, pvA[2]);
        pvA[3] = MFMA16(wd3, paA, pvA[3]);
        pvB[0] = MFMA16(wd0, paB, pvB[0]);
        pvB[1] = MFMA16(wd1, paB, pvB[1]);
        pvB[2] = MFMA16(wd2, paB, pvB[2]);
        pvB[3] = MFMA16(wd3, paB, pvB[3]);
    }
    dsA += __shfl_xor(dsA, 16, 64); dsA += __shfl_xor(dsA, 32, 64);
    dsB += __shfl_xor(dsB, 16, 64); dsB += __shfl_xor(dsB, 32, 64);

    int slot = (s*4 + dhi)*KS + kc;
    __bf16* pp = pvp + (size_t)slot*524288;
    #pragma unroll
    for (int dt=0; dt<4; dt++){
        bf16x4 oA, oB;
        #pragma unroll
        for (int i=0;i<4;i++){ oA[i] = (__bf16)pvA[dt][i]; oB[i] = (__bf16)pvB[dt][i]; }
        size_t col = (size_t)h*64 + dt*16 + lg*4;
        *reinterpret_cast<bf16x4*>(pp + ((size_t)b*1024 + nbase + lr)*256 + col)      = oA;
        *reinterpret_cast<bf16x4*>(pp + ((size_t)b*1024 + nbase + 16 + lr)*256 + col) = oB;
    }
    if (l < 16){
        dsp[(size_t)slot*8192 + ((size_t)b*4+h)*1024 + nbase + l]      = dsA;
        dsp[(size_t)slot*8192 + ((size_t)b*4+h)*1024 + nbase + 16 + l] = dsB;
    }
}

// ------- reduce: out[b][n][c] = sum_{s,dhi} wgt/DS * sum_kc pv ------------
__global__ __launch_bounds__(256) void reduce_k(const __bf16* __restrict__ pvp,
                                                const float* __restrict__ dsp,
                                                float* __restrict__ out, int KS)
{
    int idx = blockIdx.x*256 + threadIdx.x;        // 0..65535
    int c8 = idx & 31, bn = idx >> 5;
    int h = c8 >> 3;
    size_t dsoff = (size_t)(bn>>10)*4096 + (size_t)h*1024 + (bn & 1023);
    float acc[8] = {0,0,0,0,0,0,0,0};
    for (int s4=0; s4<8; s4++){
        float wgt = ((s4&3)==3) ? 2.f : 1.f;
        float fsum[8] = {0,0,0,0,0,0,0,0};
        float DS = 0.f;
        for (int kc=0; kc<KS; kc++){
            int slot = s4*KS + kc;
            bf16x8 v = ld8(pvp + (size_t)slot*524288 + (size_t)bn*256 + c8*8);
            #pragma unroll
            for (int j=0;j<8;j++) fsum[j] += (float)v[j];
            DS += dsp[(size_t)slot*8192 + dsoff];
        }
        float sc = wgt / DS;
        #pragma unroll
        for (int j=0;j<8;j++) acc[j] += fsum[j]*sc;
    }
    f32x4 o0 = {acc[0],acc[1],acc[2],acc[3]};
    f32x4 o1 = {acc[4],acc[5],acc[6],acc[7]};
    *reinterpret_cast<f32x4*>(out + (size_t)idx*8)     = o0;
    *reinterpret_cast<f32x4*>(out + (size_t)idx*8 + 4) = o1;
}

extern "C" void kernel_launch(void* const* d_in, const int* in_sizes, int n_in,
                              void* d_out, int out_size, void* d_ws, size_t ws_size,
                              hipStream_t stream)
{
    const float* x0 = (const float*)d_in[0];
    const float* x1 = (const float*)d_in[1];
    ProjArgs pa;
    for (int s=0;s<2;s++) for (int p=0;p<3;p++){
        pa.W[s*3+p]  = (const float*)d_in[2 + s*6 + p*2];
        pa.Bz[s*3+p] = (const float*)d_in[3 + s*6 + p*2];
    }
    char* wsb = (char*)d_ws;
    __bf16* Qb = (__bf16*)(wsb);                 // 2 MB (fragment order)
    __bf16* Kb = (__bf16*)(wsb + (2u<<20));      // 2 MB (fragment order)
    __bf16* Vb = (__bf16*)(wsb + (4u<<20));      // 2 MB (natural)
    __bf16* WT = (__bf16*)(wsb + (6u<<20));      // 2 MB (sigma fragment order)
    __bf16* Xb = (__bf16*)(wsb + (8u<<20));      // 2 MB (fragment order)
    __bf16* Wb = (__bf16*)(wsb + (10u<<20));     // 0.75 MB (fragment order)
    char*   pvb = wsb + (11u<<20);

    size_t base = 11u<<20;
    int KS = 1, kslog = 0;
    if (ws_size >= base + 2*(8u<<20) + 2*(256u<<10)) { KS = 2; kslog = 1; }
    __bf16* pvp = (__bf16*)pvb;                        // KS*8 MB (bf16)
    float*  dsp = (float*)(pvb + (size_t)KS*(8u<<20)); // KS*256 KB
    int kpc = 1024 / KS;

    cvt_k<<<704, 256, 0, stream>>>(x0, x1, pa, Xb, Wb);
    proj_k<<<768, 256, 0, stream>>>(Xb, Wb, pa, Qb, Kb, Vb);
    smooth_k<<<256, 256, 0, stream>>>(Vb, WT);
    attn_k<<<512*KS, 256, 0, stream>>>(Qb, Kb, WT, pvp, dsp, KS, kslog, kpc);
    reduce_k<<<256, 256, 0, stream>>>(pvp, dsp, (float*)d_out, KS);
}

// Round 7
// 51.725 us; speedup vs baseline: 3.1779x; 1.0639x over previous
//
#include <hip/hip_runtime.h>
#include <hip/hip_bf16.h>

// MultiScaleSparseSelfAttention, algebraically reduced:
//  - roll acts on (head, flatN) axes; softmax is shift-invariant over keys
//  - sum over dw collapses to P_{h,g} @ Wsum_u, Wsum = sum of v rows at {-4,-2,0,2,4}
//  - dh=+2 and dh=-2 identical (mod 4) -> weight 2
// R4: fragment-contiguous layouts; R5: 32 q-rows/wave; R6: swapped-operand
//     attention (S^T = mfma(K,Q), sigma-permuted Wsum; no LDS in K-loop).
// R7: proj stores via LDS staging -> one contiguous 8KB write per block
//     (was 16-segment scatter stores); attn KS=1 (full-K per wave, half the
//     partial traffic, no kc loop in reduce).

typedef __bf16 bf16x8 __attribute__((ext_vector_type(8)));
typedef __bf16 bf16x4 __attribute__((ext_vector_type(4)));
typedef float f32x4 __attribute__((ext_vector_type(4)));

#define MFMA16(A,B,C) __builtin_amdgcn_mfma_f32_16x16x32_bf16(A,B,C,0,0,0)

__device__ __forceinline__ bf16x8 ld8(const __bf16* p){ return *reinterpret_cast<const bf16x8*>(p); }

struct ProjArgs { const float* W[6]; const float* Bz[6]; };

// ---- cvt: f32 -> bf16 in FRAGMENT order. X: 2x(2048x256), W: 6x(256x256) ----
__global__ __launch_bounds__(256) void cvt_k(const float* __restrict__ x0,
                                             const float* __restrict__ x1,
                                             ProjArgs args,
                                             __bf16* __restrict__ Xb,
                                             __bf16* __restrict__ Wb)
{
    int g = blockIdx.x*256 + threadIdx.x;
    const float* src; __bf16* dst;
    if (g < 131072){                           // X part: s = g>>16
        int s = g >> 16;
        int E = (g & 65535)*8;                 // element offset within scale
        int blk = E >> 9, lane8 = (E >> 3) & 63;
        int row = (blk>>3)*16 + (lane8 & 15);
        int ci  = (blk&7)*32 + (lane8>>4)*8;
        src = (s ? x1 : x0) + (size_t)row*256 + ci;
        dst = Xb + (size_t)s*524288 + E;
    } else {
        int gw = g - 131072;                   // W part: sp = gw>>13
        int sp = gw >> 13;
        int E = (gw & 8191)*8;
        int blk = E >> 9, lane8 = (E >> 3) & 63;
        int co = (blk>>3)*16 + (lane8 & 15);
        int ci = (blk&7)*32 + (lane8>>4)*8;
        src = args.W[sp] + (size_t)co*256 + ci;
        dst = Wb + (size_t)sp*65536 + E;
    }
    f32x4 a = *reinterpret_cast<const f32x4*>(src);
    f32x4 b = *reinterpret_cast<const f32x4*>(src+4);
    bf16x8 o;
    #pragma unroll
    for (int j=0;j<4;j++){ o[j] = (__bf16)a[j]; o[4+j] = (__bf16)b[j]; }
    *reinterpret_cast<bf16x8*>(dst) = o;
}

// ---------------- projection ----------------
// Each block computes a 64-row x 64-col tile of one of q|k|v, stages it in
// LDS (fragment order for q/k, natural for v), then writes ONE contiguous
// 8KB global region (2 x 16B coalesced stores per thread).
__global__ __launch_bounds__(256) void proj_k(const __bf16* __restrict__ Xb,
                                              const __bf16* __restrict__ Wb,
                                              ProjArgs args,
                                              __bf16* __restrict__ Qb,
                                              __bf16* __restrict__ Kb,
                                              __bf16* __restrict__ Vb)
{
    __shared__ __bf16 stage[4096];
    int bid = blockIdx.x;
    int cg = bid % 12, rg = bid / 12;
    int tid = threadIdx.x, wv = tid >> 6, l = tid & 63;
    int lr = l & 15, lg = l >> 4;
    int s = rg >> 5;
    const __bf16* Xf = Xb + (size_t)s*524288;
    int p = cg >> 2;                       // 0=q 1=k 2=v
    const __bf16* Wf = Wb + (size_t)(s*3+p)*65536;
    const float* bp = args.Bz[s*3 + p];
    int colbase = (cg & 3)*64;
    int rowblk = ((rg & 31)*4 + wv);

    f32x4 acc[4];
    #pragma unroll
    for (int t=0;t<4;t++) acc[t] = f32x4{0.f,0.f,0.f,0.f};

    #pragma unroll
    for (int kk=0; kk<8; kk++){
        bf16x8 af = ld8(Xf + (size_t)(rowblk*8 + kk)*512 + l*8);
        #pragma unroll
        for (int ct=0; ct<4; ct++){
            bf16x8 bfv = ld8(Wf + (size_t)(((cg&3)*4 + ct)*8 + kk)*512 + l*8);
            acc[ct] = MFMA16(af, bfv, acc[ct]);
        }
    }
    float qs = (p==0) ? 0.09016844136f : 1.0f;   // (1/16)*log2(e) into Q
    #pragma unroll
    for (int ct=0; ct<4; ct++){
        int d = ct*16 + lr;                      // 0..63 within head
        float bias = bp[colbase + d];
        #pragma unroll
        for (int i=0;i<4;i++){
            float v = (acc[ct][i] + bias) * qs;
            int a;
            if (p < 2) a = wv*1024 + ((d>>5)&1)*512 + ((d>>3)&3)*128 + (lg*4+i)*8 + (d&7);
            else       a = (wv*16 + lg*4 + i)*64 + d;
            stage[a] = (__bf16)v;
        }
    }
    __syncthreads();
    int gr0 = rg*64;
    int b = (gr0 >> 10) & 1, n0 = gr0 & 1023;
    int h = cg & 3;
    int sb = s*2 + b;
    __bf16* dstb; size_t goff;
    if (p == 0){ dstb = Qb; goff = ((size_t)(sb*4 + h))*65536 + (size_t)(n0>>4)*1024; }
    else if (p == 1){ dstb = Kb; goff = ((size_t)(sb*4 + h))*65536 + (size_t)(n0>>4)*1024; }
    else { dstb = Vb; goff = ((size_t)(sb*4 + h)*1024 + n0)*64; }
    bf16x8 v0 = *reinterpret_cast<const bf16x8*>(stage + tid*16);
    bf16x8 v1 = *reinterpret_cast<const bf16x8*>(stage + tid*16 + 8);
    *reinterpret_cast<bf16x8*>(dstb + goff + (size_t)tid*16)     = v0;
    *reinterpret_cast<bf16x8*>(dstb + goff + (size_t)tid*16 + 8) = v1;
}

// ------ smoothed V^T, sigma-permuted A-fragment order: Wsig[sbu] ------
// elem(d, key m): kb = m>>5, p = sigma^{-1}(m&31);
// addr = kb*2048 + (d>>4)*512 + (p>>3)*128 + (d&15)*8 + (p&7)
// sigma^{-1}: m32<16 -> (m32>>2)*8 + (m32&3); else ((m32-16)>>2)*8+4+(m32&3)
__global__ __launch_bounds__(256) void smooth_k(const __bf16* __restrict__ Vb,
                                                __bf16* __restrict__ WT)
{
    __shared__ __bf16 Vt[72][66];
    int bid = blockIdx.x;
    int sbu = bid >> 4, n0 = (bid & 15)*64;
    int tid = threadIdx.x;
    const __bf16* Vs = Vb + (size_t)sbu*65536;
    for (int idx = tid; idx < 576; idx += 256){
        int row = idx >> 3, ch = idx & 7;
        int n = (n0 - 4 + row) & 1023;
        bf16x8 v = ld8(Vs + (size_t)n*64 + ch*8);
        #pragma unroll
        for (int j=0;j<8;j++) Vt[row][ch*8+j] = v[j];
    }
    __syncthreads();
    int w = tid >> 6, l = tid & 63;
    __bf16* dst = WT + (size_t)sbu*65536;
    int m = n0 + l;
    int kb = m >> 5, m32 = m & 31;
    int p = (m32 < 16) ? ((m32>>2)*8 + (m32&3))
                       : (((m32-16)>>2)*8 + 4 + (m32&3));
    size_t pbase = (size_t)kb*2048 + (p>>3)*128 + (p&7);
    #pragma unroll
    for (int it=0; it<16; it++){
        int d = it*4 + w;
        float sum = 0.f;
        #pragma unroll
        for (int j=0;j<5;j++) sum += (float)Vt[l + j*2][d];
        dst[pbase + (size_t)(d>>4)*512 + (d&15)*8] = (__bf16)sum;
    }
}

// ---------------- attention (swapped operands, no LDS, full-K) ----------------
// Block task = (s,b,h,dhi,qg): 4 waves x 32 q-rows, 1024 keys.
// S^T = mfma(K,Q): lane (lr=qrow, lg) holds keys {4lg+i} u {16+4lg+i}.
// exp -> pack -> B-fragment; O^T = mfma(Wsig_dt, P) accumulates d-tiles.
__global__ __launch_bounds__(256) void attn_k(const __bf16* __restrict__ Qb,
                                              const __bf16* __restrict__ Kb,
                                              const __bf16* __restrict__ WT,
                                              __bf16* __restrict__ pvp,
                                              float* __restrict__ dsp)
{
    int tid = threadIdx.x, wv = tid>>6, l = tid&63, lr = l&15, lg = l>>4;
    int t = blockIdx.x;
    int qg = t & 7; t >>= 3;
    int dhi = t & 3, h = (t>>2)&3, b = (t>>4)&1, s = (t>>5)&1;
    int dhv = (dhi==2) ? -1 : (dhi==3 ? 2 : dhi);   // {0,1,-1,2}
    int g = (h - dhv + 4) & 3;                      // K head
    int u = (h + dhv + 4) & 3;                      // V head
    int sb = s*2 + b;
    int nbase = qg*128 + wv*32;
    const __bf16* Qw = Qb + ((size_t)(sb*4 + h))*65536 + (size_t)(nbase>>4)*1024;
    const __bf16* Kg = Kb + ((size_t)(sb*4 + g))*65536;
    const __bf16* Wu = WT + ((size_t)(sb*4 + u))*65536;
    bf16x8 qa0 = ld8(Qw + l*8),        qa1 = ld8(Qw + 512 + l*8);
    bf16x8 qb0 = ld8(Qw + 1024 + l*8), qb1 = ld8(Qw + 1536 + l*8);

    const f32x4 z = {0.f,0.f,0.f,0.f};
    f32x4 pvA[4] = {z,z,z,z};
    f32x4 pvB[4] = {z,z,z,z};
    float dsA = 0.f, dsB = 0.f;

    for (int kt=0; kt<1024; kt+=32){
        const __bf16* k0 = Kg + (size_t)(kt>>4)*1024 + l*8;
        bf16x8 kf00 = ld8(k0),        kf01 = ld8(k0 + 512);
        bf16x8 kf10 = ld8(k0 + 1024), kf11 = ld8(k0 + 1536);
        const __bf16* w0 = Wu + (size_t)(kt>>5)*2048 + l*8;
        bf16x8 wd0 = ld8(w0);
        bf16x8 wd1 = ld8(w0 + 512);
        bf16x8 wd2 = ld8(w0 + 1024);
        bf16x8 wd3 = ld8(w0 + 1536);
        // S^T blocks: rows=keys, cols=qrows
        f32x4 sA0 = MFMA16(kf00, qa0, z); sA0 = MFMA16(kf01, qa1, sA0);
        f32x4 sA1 = MFMA16(kf10, qa0, z); sA1 = MFMA16(kf11, qa1, sA1);
        f32x4 sB0 = MFMA16(kf00, qb0, z); sB0 = MFMA16(kf01, qb1, sB0);
        f32x4 sB1 = MFMA16(kf10, qb0, z); sB1 = MFMA16(kf11, qb1, sB1);
        bf16x8 paA, paB;
        #pragma unroll
        for (int i=0;i<4;i++){
            float eA0 = __builtin_amdgcn_exp2f(sA0[i]);
            float eA1 = __builtin_amdgcn_exp2f(sA1[i]);
            float eB0 = __builtin_amdgcn_exp2f(sB0[i]);
            float eB1 = __builtin_amdgcn_exp2f(sB1[i]);
            dsA += eA0 + eA1;
            dsB += eB0 + eB1;
            paA[i] = (__bf16)eA0; paA[4+i] = (__bf16)eA1;
            paB[i] = (__bf16)eB0; paB[4+i] = (__bf16)eB1;
        }
        pvA[0] = MFMA16(wd0, paA, pvA[0]);
        pvA[1] = MFMA16(wd1, paA, pvA[1]);
        pvA[2] = MFMA16(wd2, paA, pvA[2]);
        pvA[3] = MFMA16(wd3, paA, pvA[3]);
        pvB[0] = MFMA16(wd0, paB, pvB[0]);
        pvB[1] = MFMA16(wd1, paB, pvB[1]);
        pvB[2] = MFMA16(wd2, paB, pvB[2]);
        pvB[3] = MFMA16(wd3, paB, pvB[3]);
    }
    dsA += __shfl_xor(dsA, 16, 64); dsA += __shfl_xor(dsA, 32, 64);
    dsB += __shfl_xor(dsB, 16, 64); dsB += __shfl_xor(dsB, 32, 64);

    int slot = s*4 + dhi;
    __bf16* pp = pvp + (size_t)slot*524288;
    #pragma unroll
    for (int dt=0; dt<4; dt++){
        bf16x4 oA, oB;
        #pragma unroll
        for (int i=0;i<4;i++){ oA[i] = (__bf16)pvA[dt][i]; oB[i] = (__bf16)pvB[dt][i]; }
        size_t col = (size_t)h*64 + dt*16 + lg*4;
        *reinterpret_cast<bf16x4*>(pp + ((size_t)b*1024 + nbase + lr)*256 + col)      = oA;
        *reinterpret_cast<bf16x4*>(pp + ((size_t)b*1024 + nbase + 16 + lr)*256 + col) = oB;
    }
    if (l < 16){
        dsp[(size_t)slot*8192 + ((size_t)b*4+h)*1024 + nbase + l]      = dsA;
        dsp[(size_t)slot*8192 + ((size_t)b*4+h)*1024 + nbase + 16 + l] = dsB;
    }
}

// ------- reduce: out[b][n][c] = sum_{s,dhi} wgt/DS * pv ------------
__global__ __launch_bounds__(256) void reduce_k(const __bf16* __restrict__ pvp,
                                                const float* __restrict__ dsp,
                                                float* __restrict__ out)
{
    int idx = blockIdx.x*256 + threadIdx.x;        // 0..65535
    int c8 = idx & 31, bn = idx >> 5;
    int h = c8 >> 3;
    size_t dsoff = (size_t)(bn>>10)*4096 + (size_t)h*1024 + (bn & 1023);
    float acc[8] = {0,0,0,0,0,0,0,0};
    #pragma unroll
    for (int s4=0; s4<8; s4++){
        float wgt = ((s4&3)==3) ? 2.f : 1.f;
        bf16x8 v = ld8(pvp + (size_t)s4*524288 + (size_t)bn*256 + c8*8);
        float DS = dsp[(size_t)s4*8192 + dsoff];
        float sc = wgt / DS;
        #pragma unroll
        for (int j=0;j<8;j++) acc[j] += (float)v[j] * sc;
    }
    f32x4 o0 = {acc[0],acc[1],acc[2],acc[3]};
    f32x4 o1 = {acc[4],acc[5],acc[6],acc[7]};
    *reinterpret_cast<f32x4*>(out + (size_t)idx*8)     = o0;
    *reinterpret_cast<f32x4*>(out + (size_t)idx*8 + 4) = o1;
}

extern "C" void kernel_launch(void* const* d_in, const int* in_sizes, int n_in,
                              void* d_out, int out_size, void* d_ws, size_t ws_size,
                              hipStream_t stream)
{
    const float* x0 = (const float*)d_in[0];
    const float* x1 = (const float*)d_in[1];
    ProjArgs pa;
    for (int s=0;s<2;s++) for (int p=0;p<3;p++){
        pa.W[s*3+p]  = (const float*)d_in[2 + s*6 + p*2];
        pa.Bz[s*3+p] = (const float*)d_in[3 + s*6 + p*2];
    }
    char* wsb = (char*)d_ws;
    __bf16* Qb = (__bf16*)(wsb);                 // 2 MB (fragment order)
    __bf16* Kb = (__bf16*)(wsb + (2u<<20));      // 2 MB (fragment order)
    __bf16* Vb = (__bf16*)(wsb + (4u<<20));      // 2 MB (natural)
    __bf16* WT = (__bf16*)(wsb + (6u<<20));      // 2 MB (sigma fragment order)
    __bf16* Xb = (__bf16*)(wsb + (8u<<20));      // 2 MB (fragment order)
    __bf16* Wb = (__bf16*)(wsb + (10u<<20));     // 0.75 MB (fragment order)
    __bf16* pvp = (__bf16*)(wsb + (11u<<20));    // 8 MB (bf16, 8 slots)
    float*  dsp = (float*)(wsb + (19u<<20));     // 256 KB

    cvt_k<<<704, 256, 0, stream>>>(x0, x1, pa, Xb, Wb);
    proj_k<<<768, 256, 0, stream>>>(Xb, Wb, pa, Qb, Kb, Vb);
    smooth_k<<<256, 256, 0, stream>>>(Vb, WT);
    attn_k<<<512, 256, 0, stream>>>(Qb, Kb, WT, pvp, dsp);
    reduce_k<<<256, 256, 0, stream>>>(pvp, dsp, (float*)d_out);
}

// Round 8
// 47.883 us; speedup vs baseline: 3.4329x; 1.0803x over previous
//
#include <hip/hip_runtime.h>
#include <hip/hip_bf16.h>

// MultiScaleSparseSelfAttention, algebraically reduced:
//  - roll acts on (head, flatN) axes; softmax is shift-invariant over keys
//  - sum over dw collapses to P_{h,g} @ Wsum_u, Wsum = sum of v rows at {-4,-2,0,2,4}
//  - dh=+2 and dh=-2 identical (mod 4) -> weight 2
// R4: fragment-contiguous layouts; R5: 32 q-rows/wave; R6: swapped-operand
//     attention; R7: LDS-staged proj stores, KS=1.
// R8: attn normalizes in-kernel (wgt/DS folded, dsp deleted); O-tile staged
//     through per-wave LDS -> coalesced 16B stores (was 4B x 64-segment
//     scatter); setprio around MFMA; unroll-2 K-loop. reduce = pure 8-way sum.

typedef __bf16 bf16x8 __attribute__((ext_vector_type(8)));
typedef __bf16 bf16x4 __attribute__((ext_vector_type(4)));
typedef float f32x4 __attribute__((ext_vector_type(4)));

#define MFMA16(A,B,C) __builtin_amdgcn_mfma_f32_16x16x32_bf16(A,B,C,0,0,0)

__device__ __forceinline__ bf16x8 ld8(const __bf16* p){ return *reinterpret_cast<const bf16x8*>(p); }

struct ProjArgs { const float* W[6]; const float* Bz[6]; };

// ---- cvt: f32 -> bf16 in FRAGMENT order. X: 2x(2048x256), W: 6x(256x256) ----
__global__ __launch_bounds__(256) void cvt_k(const float* __restrict__ x0,
                                             const float* __restrict__ x1,
                                             ProjArgs args,
                                             __bf16* __restrict__ Xb,
                                             __bf16* __restrict__ Wb)
{
    int g = blockIdx.x*256 + threadIdx.x;
    const float* src; __bf16* dst;
    if (g < 131072){                           // X part: s = g>>16
        int s = g >> 16;
        int E = (g & 65535)*8;                 // element offset within scale
        int blk = E >> 9, lane8 = (E >> 3) & 63;
        int row = (blk>>3)*16 + (lane8 & 15);
        int ci  = (blk&7)*32 + (lane8>>4)*8;
        src = (s ? x1 : x0) + (size_t)row*256 + ci;
        dst = Xb + (size_t)s*524288 + E;
    } else {
        int gw = g - 131072;                   // W part: sp = gw>>13
        int sp = gw >> 13;
        int E = (gw & 8191)*8;
        int blk = E >> 9, lane8 = (E >> 3) & 63;
        int co = (blk>>3)*16 + (lane8 & 15);
        int ci = (blk&7)*32 + (lane8>>4)*8;
        src = args.W[sp] + (size_t)co*256 + ci;
        dst = Wb + (size_t)sp*65536 + E;
    }
    f32x4 a = *reinterpret_cast<const f32x4*>(src);
    f32x4 b = *reinterpret_cast<const f32x4*>(src+4);
    bf16x8 o;
    #pragma unroll
    for (int j=0;j<4;j++){ o[j] = (__bf16)a[j]; o[4+j] = (__bf16)b[j]; }
    *reinterpret_cast<bf16x8*>(dst) = o;
}

// ---------------- projection ----------------
// Each block computes a 64x64 tile of q|k|v, stages in LDS (fragment order
// for q/k, natural for v), writes ONE contiguous 8KB region.
__global__ __launch_bounds__(256) void proj_k(const __bf16* __restrict__ Xb,
                                              const __bf16* __restrict__ Wb,
                                              ProjArgs args,
                                              __bf16* __restrict__ Qb,
                                              __bf16* __restrict__ Kb,
                                              __bf16* __restrict__ Vb)
{
    __shared__ __bf16 stage[4096];
    int bid = blockIdx.x;
    int cg = bid % 12, rg = bid / 12;
    int tid = threadIdx.x, wv = tid >> 6, l = tid & 63;
    int lr = l & 15, lg = l >> 4;
    int s = rg >> 5;
    const __bf16* Xf = Xb + (size_t)s*524288;
    int p = cg >> 2;                       // 0=q 1=k 2=v
    const __bf16* Wf = Wb + (size_t)(s*3+p)*65536;
    const float* bp = args.Bz[s*3 + p];
    int colbase = (cg & 3)*64;
    int rowblk = ((rg & 31)*4 + wv);

    f32x4 acc[4];
    #pragma unroll
    for (int t=0;t<4;t++) acc[t] = f32x4{0.f,0.f,0.f,0.f};

    #pragma unroll
    for (int kk=0; kk<8; kk++){
        bf16x8 af = ld8(Xf + (size_t)(rowblk*8 + kk)*512 + l*8);
        #pragma unroll
        for (int ct=0; ct<4; ct++){
            bf16x8 bfv = ld8(Wf + (size_t)(((cg&3)*4 + ct)*8 + kk)*512 + l*8);
            acc[ct] = MFMA16(af, bfv, acc[ct]);
        }
    }
    float qs = (p==0) ? 0.09016844136f : 1.0f;   // (1/16)*log2(e) into Q
    #pragma unroll
    for (int ct=0; ct<4; ct++){
        int d = ct*16 + lr;                      // 0..63 within head
        float bias = bp[colbase + d];
        #pragma unroll
        for (int i=0;i<4;i++){
            float v = (acc[ct][i] + bias) * qs;
            int a;
            if (p < 2) a = wv*1024 + ((d>>5)&1)*512 + ((d>>3)&3)*128 + (lg*4+i)*8 + (d&7);
            else       a = (wv*16 + lg*4 + i)*64 + d;
            stage[a] = (__bf16)v;
        }
    }
    __syncthreads();
    int gr0 = rg*64;
    int b = (gr0 >> 10) & 1, n0 = gr0 & 1023;
    int h = cg & 3;
    int sb = s*2 + b;
    __bf16* dstb; size_t goff;
    if (p == 0){ dstb = Qb; goff = ((size_t)(sb*4 + h))*65536 + (size_t)(n0>>4)*1024; }
    else if (p == 1){ dstb = Kb; goff = ((size_t)(sb*4 + h))*65536 + (size_t)(n0>>4)*1024; }
    else { dstb = Vb; goff = ((size_t)(sb*4 + h)*1024 + n0)*64; }
    bf16x8 v0 = *reinterpret_cast<const bf16x8*>(stage + tid*16);
    bf16x8 v1 = *reinterpret_cast<const bf16x8*>(stage + tid*16 + 8);
    *reinterpret_cast<bf16x8*>(dstb + goff + (size_t)tid*16)     = v0;
    *reinterpret_cast<bf16x8*>(dstb + goff + (size_t)tid*16 + 8) = v1;
}

// ------ smoothed V^T, sigma-permuted A-fragment order: Wsig[sbu] ------
__global__ __launch_bounds__(256) void smooth_k(const __bf16* __restrict__ Vb,
                                                __bf16* __restrict__ WT)
{
    __shared__ __bf16 Vt[72][66];
    int bid = blockIdx.x;
    int sbu = bid >> 4, n0 = (bid & 15)*64;
    int tid = threadIdx.x;
    const __bf16* Vs = Vb + (size_t)sbu*65536;
    for (int idx = tid; idx < 576; idx += 256){
        int row = idx >> 3, ch = idx & 7;
        int n = (n0 - 4 + row) & 1023;
        bf16x8 v = ld8(Vs + (size_t)n*64 + ch*8);
        #pragma unroll
        for (int j=0;j<8;j++) Vt[row][ch*8+j] = v[j];
    }
    __syncthreads();
    int w = tid >> 6, l = tid & 63;
    __bf16* dst = WT + (size_t)sbu*65536;
    int m = n0 + l;
    int kb = m >> 5, m32 = m & 31;
    int p = (m32 < 16) ? ((m32>>2)*8 + (m32&3))
                       : (((m32-16)>>2)*8 + 4 + (m32&3));
    size_t pbase = (size_t)kb*2048 + (p>>3)*128 + (p&7);
    #pragma unroll
    for (int it=0; it<16; it++){
        int d = it*4 + w;
        float sum = 0.f;
        #pragma unroll
        for (int j=0;j<5;j++) sum += (float)Vt[l + j*2][d];
        dst[pbase + (size_t)(d>>4)*512 + (d&15)*8] = (__bf16)sum;
    }
}

// ---------------- attention (swapped operands, full-K, normalized out) -------
// Block task = (s,b,h,dhi,qg): 4 waves x 32 q-rows, 1024 keys.
// S^T = mfma(K,Q); exp -> pack -> B-fragment; O^T = mfma(Wsig_dt, P).
// Epilogue: fold wgt/DS, stage O-tile in per-wave LDS, coalesced 16B stores.
__global__ __launch_bounds__(256) void attn_k(const __bf16* __restrict__ Qb,
                                              const __bf16* __restrict__ Kb,
                                              const __bf16* __restrict__ WT,
                                              __bf16* __restrict__ pvp)
{
    int tid = threadIdx.x, wv = tid>>6, l = tid&63, lr = l&15, lg = l>>4;
    int t = blockIdx.x;
    int qg = t & 7; t >>= 3;
    int dhi = t & 3, h = (t>>2)&3, b = (t>>4)&1, s = (t>>5)&1;
    int dhv = (dhi==2) ? -1 : (dhi==3 ? 2 : dhi);   // {0,1,-1,2}
    int g = (h - dhv + 4) & 3;                      // K head
    int u = (h + dhv + 4) & 3;                      // V head
    int sb = s*2 + b;
    int nbase = qg*128 + wv*32;
    const __bf16* Qw = Qb + ((size_t)(sb*4 + h))*65536 + (size_t)(nbase>>4)*1024;
    const __bf16* Kg = Kb + ((size_t)(sb*4 + g))*65536;
    const __bf16* Wu = WT + ((size_t)(sb*4 + u))*65536;
    bf16x8 qa0 = ld8(Qw + l*8),        qa1 = ld8(Qw + 512 + l*8);
    bf16x8 qb0 = ld8(Qw + 1024 + l*8), qb1 = ld8(Qw + 1536 + l*8);

    const f32x4 z = {0.f,0.f,0.f,0.f};
    f32x4 pvA[4] = {z,z,z,z};
    f32x4 pvB[4] = {z,z,z,z};
    float dsA = 0.f, dsB = 0.f;

    #pragma unroll 2
    for (int kt=0; kt<1024; kt+=32){
        const __bf16* k0 = Kg + (size_t)(kt>>4)*1024 + l*8;
        bf16x8 kf00 = ld8(k0),        kf01 = ld8(k0 + 512);
        bf16x8 kf10 = ld8(k0 + 1024), kf11 = ld8(k0 + 1536);
        const __bf16* w0 = Wu + (size_t)(kt>>5)*2048 + l*8;
        bf16x8 wd0 = ld8(w0);
        bf16x8 wd1 = ld8(w0 + 512);
        bf16x8 wd2 = ld8(w0 + 1024);
        bf16x8 wd3 = ld8(w0 + 1536);
        __builtin_amdgcn_s_setprio(1);
        f32x4 sA0 = MFMA16(kf00, qa0, z); sA0 = MFMA16(kf01, qa1, sA0);
        f32x4 sA1 = MFMA16(kf10, qa0, z); sA1 = MFMA16(kf11, qa1, sA1);
        f32x4 sB0 = MFMA16(kf00, qb0, z); sB0 = MFMA16(kf01, qb1, sB0);
        f32x4 sB1 = MFMA16(kf10, qb0, z); sB1 = MFMA16(kf11, qb1, sB1);
        __builtin_amdgcn_s_setprio(0);
        bf16x8 paA, paB;
        #pragma unroll
        for (int i=0;i<4;i++){
            float eA0 = __builtin_amdgcn_exp2f(sA0[i]);
            float eA1 = __builtin_amdgcn_exp2f(sA1[i]);
            float eB0 = __builtin_amdgcn_exp2f(sB0[i]);
            float eB1 = __builtin_amdgcn_exp2f(sB1[i]);
            dsA += eA0 + eA1;
            dsB += eB0 + eB1;
            paA[i] = (__bf16)eA0; paA[4+i] = (__bf16)eA1;
            paB[i] = (__bf16)eB0; paB[4+i] = (__bf16)eB1;
        }
        __builtin_amdgcn_s_setprio(1);
        pvA[0] = MFMA16(wd0, paA, pvA[0]);
        pvA[1] = MFMA16(wd1, paA, pvA[1]);
        pvA[2] = MFMA16(wd2, paA, pvA[2]);
        pvA[3] = MFMA16(wd3, paA, pvA[3]);
        pvB[0] = MFMA16(wd0, paB, pvB[0]);
        pvB[1] = MFMA16(wd1, paB, pvB[1]);
        pvB[2] = MFMA16(wd2, paB, pvB[2]);
        pvB[3] = MFMA16(wd3, paB, pvB[3]);
        __builtin_amdgcn_s_setprio(0);
    }
    dsA += __shfl_xor(dsA, 16, 64); dsA += __shfl_xor(dsA, 32, 64);
    dsB += __shfl_xor(dsB, 16, 64); dsB += __shfl_xor(dsB, 32, 64);
    float wgt = (dhi==3) ? 2.f : 1.f;
    float invA = wgt / dsA, invB = wgt / dsB;

    // stage normalized O-tile (32 rows x 64 cols) in per-wave LDS, stride 72
    __shared__ alignas(16) __bf16 ost[4][32*72];
    __bf16* S = ost[wv];
    #pragma unroll
    for (int dt=0; dt<4; dt++){
        bf16x4 oA, oB;
        #pragma unroll
        for (int i=0;i<4;i++){ oA[i] = (__bf16)(pvA[dt][i]*invA); oB[i] = (__bf16)(pvB[dt][i]*invB); }
        int c0 = dt*16 + lg*4;
        *reinterpret_cast<bf16x4*>(S + lr*72 + c0)      = oA;
        *reinterpret_cast<bf16x4*>(S + (16+lr)*72 + c0) = oB;
    }
    int slot = s*4 + dhi;
    __bf16* pp = pvp + (size_t)slot*524288 + (size_t)b*262144 + (size_t)h*64;
    #pragma unroll
    for (int it=0; it<4; it++){
        int r = it*8 + (l>>3);
        bf16x8 v = *reinterpret_cast<const bf16x8*>(S + r*72 + (l&7)*8);
        *reinterpret_cast<bf16x8*>(pp + (size_t)(nbase + r)*256 + (l&7)*8) = v;
    }
}

// ------- reduce: out[b][n][c] = sum over 8 normalized slots ------------
__global__ __launch_bounds__(256) void reduce_k(const __bf16* __restrict__ pvp,
                                                float* __restrict__ out)
{
    int idx = blockIdx.x*256 + threadIdx.x;        // 0..65535
    size_t off = (size_t)idx*8;
    float acc[8] = {0,0,0,0,0,0,0,0};
    #pragma unroll
    for (int s4=0; s4<8; s4++){
        bf16x8 v = ld8(pvp + (size_t)s4*524288 + off);
        #pragma unroll
        for (int j=0;j<8;j++) acc[j] += (float)v[j];
    }
    f32x4 o0 = {acc[0],acc[1],acc[2],acc[3]};
    f32x4 o1 = {acc[4],acc[5],acc[6],acc[7]};
    *reinterpret_cast<f32x4*>(out + off)     = o0;
    *reinterpret_cast<f32x4*>(out + off + 4) = o1;
}

extern "C" void kernel_launch(void* const* d_in, const int* in_sizes, int n_in,
                              void* d_out, int out_size, void* d_ws, size_t ws_size,
                              hipStream_t stream)
{
    const float* x0 = (const float*)d_in[0];
    const float* x1 = (const float*)d_in[1];
    ProjArgs pa;
    for (int s=0;s<2;s++) for (int p=0;p<3;p++){
        pa.W[s*3+p]  = (const float*)d_in[2 + s*6 + p*2];
        pa.Bz[s*3+p] = (const float*)d_in[3 + s*6 + p*2];
    }
    char* wsb = (char*)d_ws;
    __bf16* Qb = (__bf16*)(wsb);                 // 2 MB (fragment order)
    __bf16* Kb = (__bf16*)(wsb + (2u<<20));      // 2 MB (fragment order)
    __bf16* Vb = (__bf16*)(wsb + (4u<<20));      // 2 MB (natural)
    __bf16* WT = (__bf16*)(wsb + (6u<<20));      // 2 MB (sigma fragment order)
    __bf16* Xb = (__bf16*)(wsb + (8u<<20));      // 2 MB (fragment order)
    __bf16* Wb = (__bf16*)(wsb + (10u<<20));     // 0.75 MB (fragment order)
    __bf16* pvp = (__bf16*)(wsb + (11u<<20));    // 8 MB (bf16, 8 normalized slots)

    cvt_k<<<704, 256, 0, stream>>>(x0, x1, pa, Xb, Wb);
    proj_k<<<768, 256, 0, stream>>>(Xb, Wb, pa, Qb, Kb, Vb);
    smooth_k<<<256, 256, 0, stream>>>(Vb, WT);
    attn_k<<<512, 256, 0, stream>>>(Qb, Kb, WT, pvp);
    reduce_k<<<256, 256, 0, stream>>>(pvp, (float*)d_out);
}